// Round 5
// baseline (319.150 us; speedup 1.0000x reference)
//
#include <hip/hip_runtime.h>

#define IX 1440
#define IY 720
#define NB 4
#define NCH 12
#define PLANE (IY * IX)            // 1,036,800
#define NOUT (NB * NCH * PLANE)    // 49,766,400
#define NTHREADS (NB * PLANE / 2)  // 2,073,600 threads, 2 px each
#define NWG (NTHREADS / 256)       // 8100
#define SWZ_Q (NWG / 8)            // 1012
#define SWZ_R (NWG % 8)            // 4

typedef float f2v __attribute__((ext_vector_type(2)));

__global__ void zero_ws_kernel(double* ws) {
    if (threadIdx.x < 4) ws[threadIdx.x] = 0.0;
}

__device__ __forceinline__ void ld2(const float* p, float o[2]) {
    const f2v v = *reinterpret_cast<const f2v*>(p);
    o[0] = v.x; o[1] = v.y;
}

__global__ __launch_bounds__(256, 6) void euler_kernel(
    const float* __restrict__ Field,
    const float* __restrict__ W,
    const float* __restrict__ bvec,
    const float* __restrict__ thermal,
    float* __restrict__ out,
    double* __restrict__ ws)
{
    __shared__ float sW[180];
    __shared__ float sB[16];
    __shared__ float sRed[4][4];

    const int t = threadIdx.x;
    if (t < 180) sW[t] = W[t];
    if (t < 15)  sB[t] = bvec[t];
    const float th = thermal[0];
    __syncthreads();

    // bijective XCD-slab swizzle (m204)
    const int bid = blockIdx.x;
    const int xcd = bid & 7, pos = bid >> 3;
    const int wg  = (xcd < SWZ_R ? xcd * (SWZ_Q + 1)
                                 : SWZ_R * (SWZ_Q + 1) + (xcd - SWZ_R) * SWZ_Q) + pos;

    const int tid = wg * 256 + t;
    const int xi  = tid % 720;          // which float2 in the row
    const int row = tid / 720;          // global (b,y) row
    const int x2  = xi * 2;
    const int y   = row % IY;
    const int b   = row / IY;

    const int xm  = (x2 == 0)      ? IX - 2 : x2 - 2;
    const int xp  = (x2 == IX - 2) ? 0      : x2 + 2;
    const int ym1 = (y == 0)      ? IY - 1       : y - 1;
    const int ym2 = (y < 2)       ? y + IY - 2   : y - 2;
    const int yp1 = (y == IY - 1) ? 0            : y + 1;
    const int yp2 = (y >= IY - 2) ? y - (IY - 2) : y + 2;

    const float* base = Field + (size_t)b * NCH * PLANE;
    const size_t ro = (size_t)y * IX;

    // center values, all 12 channels (batched independent loads)
    float ctr[12][2];
#pragma unroll
    for (int c = 0; c < 12; ++c) ld2(base + (size_t)c * PLANE + ro + x2, ctr[c]);

    // ml[12..14] ("o") — needed by every physics term
    float ml12[3][2];
#pragma unroll
    for (int z = 0; z < 3; ++z) {
#pragma unroll
        for (int j = 0; j < 2; ++j) ml12[z][j] = sB[12 + z];
#pragma unroll
        for (int cc = 0; cc < 12; ++cc) {
            const float wv = sW[(12 + z) * 12 + cc];
#pragma unroll
            for (int j = 0; j < 2; ++j) ml12[z][j] = fmaf(wv, ctr[cc][j], ml12[z][j]);
        }
    }

    float c2 = 0.f, ef2 = 0.f, pp2 = 0.f, xy2 = 0.f;
    float* ob = out + (size_t)b * NCH * PLANE + ro + x2;

    // z-group order: per z process f = 3, 0, 1, 2  →  fdx9/fdy9/con are transient
#pragma unroll
    for (int z = 0; z < 3; ++z) {
        const int zp = (z == 2) ? 0 : z + 1;
        const int zm = (z == 0) ? 2 : z - 1;
        const float invp = (z == 0) ? 0.1f : (z == 1) ? (1.0f / 8.5f) : 0.2f;

        float fdx9[2], fdy9[2];
        float conz[2];
#pragma unroll
        for (int j = 0; j < 2; ++j) conz[j] = 0.5f * (ml12[zp][j] - ml12[zm][j]);

#pragma unroll
        for (int fi = 0; fi < 4; ++fi) {
            const int f = (fi == 0) ? 3 : fi - 1;   // 3,0,1,2
            const int c = f * 3 + z;
            const float* pc = base + (size_t)c * PLANE;

            float vxm[2], vxp[2], vm2[2], vm1[2], vp1[2], vp2[2];
            ld2(pc + ro + xm, vxm);
            ld2(pc + ro + xp, vxp);
            ld2(pc + (size_t)ym2 * IX + x2, vm2);
            ld2(pc + (size_t)ym1 * IX + x2, vm1);
            ld2(pc + (size_t)yp1 * IX + x2, vp1);
            ld2(pc + (size_t)yp2 * IX + x2, vp2);

            // 6-wide x window: [xm(2) | ctr(2) | xp(2)], pixel j at w[2+j]
            float w[6];
            w[0] = vxm[0]; w[1] = vxm[1];
            w[2] = ctr[c][0]; w[3] = ctr[c][1];
            w[4] = vxp[0]; w[5] = vxp[1];

            float fdx[2], fdy[2];
#pragma unroll
            for (int j = 0; j < 2; ++j) {
                fdx[j] = (w[j] - w[j + 4] + 8.0f * (w[j + 3] - w[j + 1])) * (1.0f / 12.0f);
                fdy[j] = (vm2[j] - vp2[j] + 8.0f * (vp1[j] - vm1[j])) * (1.0f / 12.0f);
            }

            float mlc[2];
#pragma unroll
            for (int j = 0; j < 2; ++j) mlc[j] = sB[c];
#pragma unroll
            for (int cc = 0; cc < 12; ++cc) {
                const float wv = sW[c * 12 + cc];
#pragma unroll
                for (int j = 0; j < 2; ++j) mlc[j] = fmaf(wv, ctr[cc][j], mlc[j]);
            }

            if (f == 3) {
#pragma unroll
                for (int j = 0; j < 2; ++j) { fdx9[j] = fdx[j]; fdy9[j] = fdy[j]; }
            }
            if (f == 0) {
#pragma unroll
                for (int j = 0; j < 2; ++j) conz[j] += fdx[j];
            }
            if (f == 1) {
#pragma unroll
                for (int j = 0; j < 2; ++j) conz[j] += fdy[j];
            }

            float st[2];
#pragma unroll
            for (int j = 0; j < 2; ++j) {
                const float fdz = 0.5f * (ctr[f * 3 + zp][j] - ctr[f * 3 + zm][j]);
                const float xyd = -ctr[z][j] * fdx[j] - ctr[3 + z][j] * fdy[j];
                float ph;
                if      (f == 0) ph = -fdx9[j];
                else if (f == 1) ph = -fdy9[j];
                else if (f == 2) ph = th * ctr[6 + z][j] * invp * ml12[z][j];
                else             ph = 0.0f;
                const float phys = xyd - ml12[z][j] * fdz + ph;
                st[j] = ctr[c][j] + mlc[j] + phys;
                ef2 = fmaf(mlc[j],  mlc[j],  ef2);
                pp2 = fmaf(phys,    phys,    pp2);
                xy2 = fmaf(xyd,     xyd,     xy2);
            }
            // output is never re-read: keep it out of L2
            f2v sv; sv.x = st[0]; sv.y = st[1];
            __builtin_nontemporal_store(sv, reinterpret_cast<f2v*>(ob + (size_t)c * PLANE));
        }

#pragma unroll
        for (int j = 0; j < 2; ++j) c2 = fmaf(conz[j], conz[j], c2);
    }

    // block reduction of the 4 partial sums
    float vals[4] = { c2, ef2, pp2, xy2 };
    const int lane = t & 63;
    const int wv   = t >> 6;
#pragma unroll
    for (int i = 0; i < 4; ++i) {
        float v = vals[i];
        for (int off = 32; off > 0; off >>= 1) v += __shfl_down(v, off, 64);
        if (lane == 0) sRed[wv][i] = v;
    }
    __syncthreads();
    if (t < 4) {
        const double s = (double)sRed[0][t] + (double)sRed[1][t]
                       + (double)sRed[2][t] + (double)sRed[3][t];
        atomicAdd(&ws[t], s);
    }
}

__global__ void finalize_kernel(const double* __restrict__ ws, float* __restrict__ out) {
    if (threadIdx.x == 0) {
        out[NOUT + 0] = (float)(ws[0] / (double)(NB * 3 * PLANE));
        out[NOUT + 1] = (float)(ws[1] / (double)NOUT);
        out[NOUT + 2] = (float)(ws[2] / (double)NOUT);
        out[NOUT + 3] = (float)(ws[3] / (double)NOUT);
    }
}

extern "C" void kernel_launch(void* const* d_in, const int* in_sizes, int n_in,
                              void* d_out, int out_size, void* d_ws, size_t ws_size,
                              hipStream_t stream) {
    const float* Field   = (const float*)d_in[0];
    const float* W       = (const float*)d_in[1];
    const float* bvec    = (const float*)d_in[2];
    const float* thermal = (const float*)d_in[3];
    float*  out = (float*)d_out;
    double* ws  = (double*)d_ws;

    zero_ws_kernel<<<1, 64, 0, stream>>>(ws);
    euler_kernel<<<NWG, 256, 0, stream>>>(Field, W, bvec, thermal, out, ws);
    finalize_kernel<<<1, 64, 0, stream>>>(ws, out);
}

// Round 6
// 123.018 us; speedup vs baseline: 2.5943x; 2.5943x over previous
//
#include <hip/hip_runtime.h>

#define IX 1440
#define IY 720
#define NB 4
#define NCH 12
#define PLANE (IY * IX)            // 1,036,800
#define NOUT (NB * NCH * PLANE)    // 49,766,400
#define NTHREADS (NB * PLANE / 2)  // 2,073,600 threads, 2 px each
#define NWG (NTHREADS / 256)       // 8100
#define SWZ_Q (NWG / 8)            // 1012
#define SWZ_R (NWG % 8)            // 4

typedef float f2v __attribute__((ext_vector_type(2)));

__global__ void zero_ws_kernel(double* ws) {
    if (threadIdx.x < 4) ws[threadIdx.x] = 0.0;
}

__device__ __forceinline__ void ld2(const float* p, float o[2]) {
    const f2v v = *reinterpret_cast<const f2v*>(p);
    o[0] = v.x; o[1] = v.y;
}

__global__ __launch_bounds__(256) void euler_kernel(
    const float* __restrict__ Field,
    const float* __restrict__ W,
    const float* __restrict__ bvec,
    const float* __restrict__ thermal,
    float* __restrict__ out,
    double* __restrict__ ws)
{
    __shared__ float sW[180];
    __shared__ float sB[16];
    __shared__ float sRed[4][4];

    const int t = threadIdx.x;
    if (t < 180) sW[t] = W[t];
    if (t < 15)  sB[t] = bvec[t];
    const float th = thermal[0];
    __syncthreads();

    // bijective XCD-slab swizzle (m204)
    const int bid = blockIdx.x;
    const int xcd = bid & 7, pos = bid >> 3;
    const int wg  = (xcd < SWZ_R ? xcd * (SWZ_Q + 1)
                                 : SWZ_R * (SWZ_Q + 1) + (xcd - SWZ_R) * SWZ_Q) + pos;

    const int tid = wg * 256 + t;
    const int xi  = tid % 720;          // which float2 in the row
    const int row = tid / 720;          // global (b,y) row
    const int x2  = xi * 2;
    const int y   = row % IY;
    const int b   = row / IY;

    const int xm  = (x2 == 0)      ? IX - 2 : x2 - 2;
    const int xp  = (x2 == IX - 2) ? 0      : x2 + 2;
    const int ym1 = (y == 0)      ? IY - 1       : y - 1;
    const int ym2 = (y < 2)       ? y + IY - 2   : y - 2;
    const int yp1 = (y == IY - 1) ? 0            : y + 1;
    const int yp2 = (y >= IY - 2) ? y - (IY - 2) : y + 2;

    const float* base = Field + (size_t)b * NCH * PLANE;
    const size_t ro = (size_t)y * IX;

    // center values, all 12 channels (batched independent loads)
    float ctr[12][2];
#pragma unroll
    for (int c = 0; c < 12; ++c) ld2(base + (size_t)c * PLANE + ro + x2, ctr[c]);

    // ml[12..14] ("o") — needed by every physics term
    float ml12[3][2];
#pragma unroll
    for (int z = 0; z < 3; ++z) {
#pragma unroll
        for (int j = 0; j < 2; ++j) ml12[z][j] = sB[12 + z];
#pragma unroll
        for (int cc = 0; cc < 12; ++cc) {
            const float wv = sW[(12 + z) * 12 + cc];
#pragma unroll
            for (int j = 0; j < 2; ++j) ml12[z][j] = fmaf(wv, ctr[cc][j], ml12[z][j]);
        }
    }

    float c2 = 0.f, ef2 = 0.f, pp2 = 0.f, xy2 = 0.f;
    float* ob = out + (size_t)b * NCH * PLANE + ro + x2;

    // z-group order: per z process f = 3, 0, 1, 2  →  fdx9/fdy9/con are transient
#pragma unroll
    for (int z = 0; z < 3; ++z) {
        const int zp = (z == 2) ? 0 : z + 1;
        const int zm = (z == 0) ? 2 : z - 1;
        const float invp = (z == 0) ? 0.1f : (z == 1) ? (1.0f / 8.5f) : 0.2f;

        float fdx9[2], fdy9[2];
        float conz[2];
#pragma unroll
        for (int j = 0; j < 2; ++j) conz[j] = 0.5f * (ml12[zp][j] - ml12[zm][j]);

#pragma unroll
        for (int fi = 0; fi < 4; ++fi) {
            const int f = (fi == 0) ? 3 : fi - 1;   // 3,0,1,2
            const int c = f * 3 + z;
            const float* pc = base + (size_t)c * PLANE;

            float vxm[2], vxp[2], vm2[2], vm1[2], vp1[2], vp2[2];
            ld2(pc + ro + xm, vxm);
            ld2(pc + ro + xp, vxp);
            ld2(pc + (size_t)ym2 * IX + x2, vm2);
            ld2(pc + (size_t)ym1 * IX + x2, vm1);
            ld2(pc + (size_t)yp1 * IX + x2, vp1);
            ld2(pc + (size_t)yp2 * IX + x2, vp2);

            // 6-wide x window: [xm(2) | ctr(2) | xp(2)], pixel j at w[2+j]
            float w[6];
            w[0] = vxm[0]; w[1] = vxm[1];
            w[2] = ctr[c][0]; w[3] = ctr[c][1];
            w[4] = vxp[0]; w[5] = vxp[1];

            float fdx[2], fdy[2];
#pragma unroll
            for (int j = 0; j < 2; ++j) {
                fdx[j] = (w[j] - w[j + 4] + 8.0f * (w[j + 3] - w[j + 1])) * (1.0f / 12.0f);
                fdy[j] = (vm2[j] - vp2[j] + 8.0f * (vp1[j] - vm1[j])) * (1.0f / 12.0f);
            }

            float mlc[2];
#pragma unroll
            for (int j = 0; j < 2; ++j) mlc[j] = sB[c];
#pragma unroll
            for (int cc = 0; cc < 12; ++cc) {
                const float wv = sW[c * 12 + cc];
#pragma unroll
                for (int j = 0; j < 2; ++j) mlc[j] = fmaf(wv, ctr[cc][j], mlc[j]);
            }

            if (f == 3) {
#pragma unroll
                for (int j = 0; j < 2; ++j) { fdx9[j] = fdx[j]; fdy9[j] = fdy[j]; }
            }
            if (f == 0) {
#pragma unroll
                for (int j = 0; j < 2; ++j) conz[j] += fdx[j];
            }
            if (f == 1) {
#pragma unroll
                for (int j = 0; j < 2; ++j) conz[j] += fdy[j];
            }

            float st[2];
#pragma unroll
            for (int j = 0; j < 2; ++j) {
                const float fdz = 0.5f * (ctr[f * 3 + zp][j] - ctr[f * 3 + zm][j]);
                const float xyd = -ctr[z][j] * fdx[j] - ctr[3 + z][j] * fdy[j];
                float ph;
                if      (f == 0) ph = -fdx9[j];
                else if (f == 1) ph = -fdy9[j];
                else if (f == 2) ph = th * ctr[6 + z][j] * invp * ml12[z][j];
                else             ph = 0.0f;
                const float phys = xyd - ml12[z][j] * fdz + ph;
                st[j] = ctr[c][j] + mlc[j] + phys;
                ef2 = fmaf(mlc[j],  mlc[j],  ef2);
                pp2 = fmaf(phys,    phys,    pp2);
                xy2 = fmaf(xyd,     xyd,     xy2);
            }
            // output is never re-read: keep it out of L2
            f2v sv; sv.x = st[0]; sv.y = st[1];
            __builtin_nontemporal_store(sv, reinterpret_cast<f2v*>(ob + (size_t)c * PLANE));
        }

#pragma unroll
        for (int j = 0; j < 2; ++j) c2 = fmaf(conz[j], conz[j], c2);
    }

    // block reduction of the 4 partial sums
    float vals[4] = { c2, ef2, pp2, xy2 };
    const int lane = t & 63;
    const int wv   = t >> 6;
#pragma unroll
    for (int i = 0; i < 4; ++i) {
        float v = vals[i];
        for (int off = 32; off > 0; off >>= 1) v += __shfl_down(v, off, 64);
        if (lane == 0) sRed[wv][i] = v;
    }
    __syncthreads();
    if (t < 4) {
        const double s = (double)sRed[0][t] + (double)sRed[1][t]
                       + (double)sRed[2][t] + (double)sRed[3][t];
        atomicAdd(&ws[t], s);
    }
}

__global__ void finalize_kernel(const double* __restrict__ ws, float* __restrict__ out) {
    if (threadIdx.x == 0) {
        out[NOUT + 0] = (float)(ws[0] / (double)(NB * 3 * PLANE));
        out[NOUT + 1] = (float)(ws[1] / (double)NOUT);
        out[NOUT + 2] = (float)(ws[2] / (double)NOUT);
        out[NOUT + 3] = (float)(ws[3] / (double)NOUT);
    }
}

extern "C" void kernel_launch(void* const* d_in, const int* in_sizes, int n_in,
                              void* d_out, int out_size, void* d_ws, size_t ws_size,
                              hipStream_t stream) {
    const float* Field   = (const float*)d_in[0];
    const float* W       = (const float*)d_in[1];
    const float* bvec    = (const float*)d_in[2];
    const float* thermal = (const float*)d_in[3];
    float*  out = (float*)d_out;
    double* ws  = (double*)d_ws;

    zero_ws_kernel<<<1, 64, 0, stream>>>(ws);
    euler_kernel<<<NWG, 256, 0, stream>>>(Field, W, bvec, thermal, out, ws);
    finalize_kernel<<<1, 64, 0, stream>>>(ws, out);
}